// Round 14
// baseline (213.515 us; speedup 1.0000x reference)
//
#include <hip/hip_runtime.h>
#include <hip/hip_bf16.h>
#include <cstdint>
#include <cstddef>

typedef __bf16 bf16x8 __attribute__((ext_vector_type(8)));
typedef __bf16 bf16x4 __attribute__((ext_vector_type(4)));
typedef __bf16 bf16x2 __attribute__((ext_vector_type(2)));
typedef float  f32x4  __attribute__((ext_vector_type(4)));

static constexpr int TSEQ  = 2048;
static constexpr int DM    = 1024;
static constexpr int NH    = 16;
static constexpr int HD    = 64;
static constexpr int BATCH = 4;
// exp(s/8) = 2^(s * log2(e)/8)
static constexpr float SCL = 0.18033688011112042f;

// async global->LDS, 16B per lane; LDS dest is wave-uniform base + lane*16
__device__ __forceinline__ void gload16(const __bf16* g, __bf16* l) {
  __builtin_amdgcn_global_load_lds((const __attribute__((address_space(1))) void*)g,
                                   (__attribute__((address_space(3))) void*)l, 16, 0, 0);
}

#define PBAR()   asm volatile("s_barrier" ::: "memory")

// ---------------- fp32 -> bf16 convert ----------------
__global__ __launch_bounds__(256) void cvt_kernel(const float* __restrict__ in,
                                                  __bf16* __restrict__ out, int n4) {
  int i = blockIdx.x * 256 + threadIdx.x;
  if (i < n4) {
    float4 v = reinterpret_cast<const float4*>(in)[i];
    bf16x4 o;
    o[0] = (__bf16)v.x; o[1] = (__bf16)v.y; o[2] = (__bf16)v.z; o[3] = (__bf16)v.w;
    reinterpret_cast<bf16x4*>(out)[i] = o;
  }
}

// 4 weight matrices in one launch (blockIdx.y selects)
__global__ __launch_bounds__(256) void cvt4_kernel(
    const float* __restrict__ a, const float* __restrict__ bsrc,
    const float* __restrict__ c, const float* __restrict__ d,
    __bf16* __restrict__ oa, __bf16* __restrict__ ob,
    __bf16* __restrict__ oc, __bf16* __restrict__ od, int n4) {
  const float* src = (blockIdx.y == 0) ? a : (blockIdx.y == 1) ? bsrc
                    : (blockIdx.y == 2) ? c : d;
  __bf16* dst = (blockIdx.y == 0) ? oa : (blockIdx.y == 1) ? ob
               : (blockIdx.y == 2) ? oc : od;
  int i = blockIdx.x * 256 + threadIdx.x;
  if (i < n4) {
    float4 v = reinterpret_cast<const float4*>(src)[i];
    bf16x4 o;
    o[0] = (__bf16)v.x; o[1] = (__bf16)v.y; o[2] = (__bf16)v.z; o[3] = (__bf16)v.w;
    reinterpret_cast<bf16x4*>(dst)[i] = o;
  }
}

// ---------------- QKV GEMM: 256x192 tile, BK=64, 4 WAVES (1 wave/SIMD) ----------------
// LDS-read-BW model (validated R13: 466cy MFMA / 1600cy LDS = 29% = measured
// MfmaUtil): frag bytes/MFMA scale as (1/M_w + 1/N_w). Halving waves doubles
// the per-wave register budget (512 @ 1 wave/EU) -> wave tile 128x96 (acc 192
// AGPR + ~115 VGPR frag/addr = ~340 of 512). LDS/K-tile 204->140 KB for the
// same 384 MFMA -> ceiling ~43%. No TLP at 1 wave/SIMD: compiler ILP over the
// 28 live frag regs covers ds_read latency; issue-early/drain-late covers HBM.
__global__ __launch_bounds__(256, 1) void gemm_qkv_kernel(
    const __bf16* __restrict__ A, const __bf16* __restrict__ Wqkv,
    const float* __restrict__ b0, const float* __restrict__ b1,
    const float* __restrict__ b2, __bf16* __restrict__ QKVp) {
  __shared__ __align__(16) __bf16 lA[2 * 256 * 64];   // 64 KB
  __shared__ __align__(16) __bf16 lB[2 * 192 * 64];   // 48 KB
  const int flat = blockIdx.x;                 // 0..511
  const int xcd = flat & 7, idx = flat >> 3;   // idx 0..63
  const int mi = xcd * 4 + (idx & 3);          // 0..31
  const int nig = idx >> 2;                    // 0..15
  const int i0 = mi * 256, o0 = nig * 192;

  const int tid = threadIdx.x;                 // 0..255
  const int l = tid & 63, lr = l & 15, lg = l >> 4;
  const int w = tid >> 6;                      // 0..3
  const int wr = w >> 1, wc = w & 1;           // wave tile: rows wr*128, cols wc*96

  f32x4 acc[8][6];
  const f32x4 fzero = {0.f, 0.f, 0.f, 0.f};
#pragma unroll
  for (int mm = 0; mm < 8; ++mm)
#pragma unroll
    for (int ni = 0; ni < 6; ++ni) acc[mm][ni] = fzero;

  const int s_row = tid >> 3;                  // 0..31 (32 rows per gload round)
  const int s_cc  = tid & 7;
  const __bf16* Ab = A + (size_t)i0 * DM;
  const __bf16* Wb = Wqkv + (size_t)o0 * DM;

  auto stageA = [&](int buf, int kt, int rr) {
    int row = rr * 32 + s_row;
    gload16(Ab + (size_t)row * DM + kt * 64 + ((s_cc ^ (row & 7)) << 3),
            lA + buf * 16384 + rr * 2048 + tid * 8);
  };
  auto stageB = [&](int buf, int kt, int rr) {
    int row = rr * 32 + s_row;
    gload16(Wb + (size_t)row * DM + kt * 64 + ((s_cc ^ (row & 7)) << 3),
            lB + buf * 12288 + rr * 2048 + tid * 8);
  };
  auto rd = [&](const __bf16* base, int row, int ks) {
    int chunk = (ks * 4 + lg) ^ (row & 7);
    return *(const bf16x8*)(base + row * 64 + chunk * 8);
  };

  const int NT = DM / 64;                      // 16 K-tiles

  // prologue: stage tile 0, full drain once
#pragma unroll
  for (int rr = 0; rr < 8; ++rr) stageA(0, 0, rr);
#pragma unroll
  for (int rr = 0; rr < 6; ++rr) stageB(0, 0, rr);
  asm volatile("s_waitcnt vmcnt(0)" ::: "memory");
  __syncthreads();

  for (int t = 0; t < NT; ++t) {
    const int cur = t & 1;
    // issue next tile's loads early -> land under this tile's reads + MFMA
    if (t + 1 < NT) {
      const int nxt = cur ^ 1;
#pragma unroll
      for (int rr = 0; rr < 8; ++rr) stageA(nxt, t + 1, rr);
#pragma unroll
      for (int rr = 0; rr < 6; ++rr) stageB(nxt, t + 1, rr);
    }

    const __bf16* cA = lA + cur * 16384;
    const __bf16* cB = lB + cur * 12288;

    bf16x8 af[8][2], bf[6][2];
#pragma unroll
    for (int mm = 0; mm < 8; ++mm)
#pragma unroll
      for (int ks = 0; ks < 2; ++ks)
        af[mm][ks] = rd(cA, wr * 128 + mm * 16 + lr, ks);
#pragma unroll
    for (int ni = 0; ni < 6; ++ni)
#pragma unroll
      for (int ks = 0; ks < 2; ++ks)
        bf[ni][ks] = rd(cB, wc * 96 + ni * 16 + lr, ks);

    __builtin_amdgcn_s_setprio(1);
#pragma unroll
    for (int mm = 0; mm < 8; ++mm)
#pragma unroll
      for (int ni = 0; ni < 6; ++ni)
#pragma unroll
        for (int ks = 0; ks < 2; ++ks)
          acc[mm][ni] = __builtin_amdgcn_mfma_f32_16x16x32_bf16(
              af[mm][ks], bf[ni][ks], acc[mm][ni], 0, 0, 0);
    __builtin_amdgcn_s_setprio(0);

    if (t + 1 < NT) {
      // drain next tile's loads AFTER compute (latency hidden), one barrier
      asm volatile("s_waitcnt vmcnt(0)" ::: "memory");
      __syncthreads();
    }
  }

#pragma unroll
  for (int ni = 0; ni < 6; ++ni) {
    int col = o0 + wc * 96 + ni * 16 + lr;     // global col in [0,3072)
    int z = col >> 10, cin = col & 1023;       // uniform z per 16-col group
    const float* bp = (z == 0) ? b0 : (z == 1) ? b1 : b2;
    float bb = bp[cin];
    __bf16* O = QKVp + (size_t)z * 8192 * DM;
#pragma unroll
    for (int mm = 0; mm < 8; ++mm) {
      int row = i0 + wr * 128 + mm * 16 + lg * 4;
#pragma unroll
      for (int r = 0; r < 4; ++r)
        O[(size_t)(row + r) * DM + cin] = (__bf16)(acc[mm][ni][r] + bb);
    }
  }
}

// ---------------- out-proj GEMM: 128x256 tile, grid 256 ----------------
template <typename OUT_T>
__device__ __forceinline__ void gemm_body2(
    const __bf16* __restrict__ A, const __bf16* __restrict__ W,
    const float* __restrict__ bias, OUT_T* __restrict__ C,
    int i0, int o0, __bf16* lA, __bf16* lB) {
  const int tid = threadIdx.x;          // 0..511
  const int l = tid & 63, lr = l & 15, lg = l >> 4;
  const int w = tid >> 6;
  const int wr = w >> 2, wc = w & 3;

  f32x4 acc[4][4];
  const f32x4 fzero = {0.f, 0.f, 0.f, 0.f};
#pragma unroll
  for (int mi = 0; mi < 4; ++mi)
#pragma unroll
    for (int ni = 0; ni < 4; ++ni) acc[mi][ni] = fzero;

  const int s_row = tid >> 3;
  const int s_cc  = tid & 7;
  const int NT = DM / 64;  // 16

  {
#pragma unroll
    for (int n = 0; n < 2; ++n) {
      int row = n * 64 + s_row;
      gload16(A + (size_t)(i0 + row) * DM + ((s_cc ^ (row & 7)) << 3),
              lA + n * 4096 + tid * 8);
    }
#pragma unroll
    for (int n = 0; n < 4; ++n) {
      int row = n * 64 + s_row;
      gload16(W + (size_t)(o0 + row) * DM + ((s_cc ^ (row & 7)) << 3),
              lB + n * 4096 + tid * 8);
    }
  }
  asm volatile("s_waitcnt vmcnt(0)" ::: "memory");
  __syncthreads();

  for (int t = 0; t < NT; ++t) {
    const int cur = t & 1;
    if (t + 1 < NT) {
      const int k0 = (t + 1) * 64;
      const int nxt = cur ^ 1;
#pragma unroll
      for (int n = 0; n < 2; ++n) {
        int row = n * 64 + s_row;
        gload16(A + (size_t)(i0 + row) * DM + k0 + ((s_cc ^ (row & 7)) << 3),
                lA + nxt * 8192 + n * 4096 + tid * 8);
      }
#pragma unroll
      for (int n = 0; n < 4; ++n) {
        int row = n * 64 + s_row;
        gload16(W + (size_t)(o0 + row) * DM + k0 + ((s_cc ^ (row & 7)) << 3),
                lB + nxt * 16384 + n * 4096 + tid * 8);
      }
    }

    const __bf16* cA = lA + cur * 8192;
    const __bf16* cB = lB + cur * 16384;

    bf16x8 af[4][2], bf_[2][2];
#pragma unroll
    for (int mi = 0; mi < 4; ++mi)
#pragma unroll
      for (int ks = 0; ks < 2; ++ks) {
        int row = wr * 64 + mi * 16 + lr;
        int chunk = (ks * 4 + lg) ^ (row & 7);
        af[mi][ks] = *(const bf16x8*)(cA + row * 64 + chunk * 8);
      }
#pragma unroll
    for (int ni = 0; ni < 2; ++ni)
#pragma unroll
      for (int ks = 0; ks < 2; ++ks) {
        int row = wc * 64 + ni * 16 + lr;
        int chunk = (ks * 4 + lg) ^ (row & 7);
        bf_[ni][ks] = *(const bf16x8*)(cB + row * 64 + chunk * 8);
      }
    __builtin_amdgcn_s_setprio(1);
#pragma unroll
    for (int mi = 0; mi < 4; ++mi)
#pragma unroll
      for (int ni = 0; ni < 2; ++ni)
#pragma unroll
        for (int ks = 0; ks < 2; ++ks)
          acc[mi][ni] = __builtin_amdgcn_mfma_f32_16x16x32_bf16(
              af[mi][ks], bf_[ni][ks], acc[mi][ni], 0, 0, 0);
    __builtin_amdgcn_s_setprio(0);

#pragma unroll
    for (int ni = 0; ni < 2; ++ni)
#pragma unroll
      for (int ks = 0; ks < 2; ++ks) {
        int row = wc * 64 + (ni + 2) * 16 + lr;
        int chunk = (ks * 4 + lg) ^ (row & 7);
        bf_[ni][ks] = *(const bf16x8*)(cB + row * 64 + chunk * 8);
      }
    __builtin_amdgcn_s_setprio(1);
#pragma unroll
    for (int mi = 0; mi < 4; ++mi)
#pragma unroll
      for (int ni = 0; ni < 2; ++ni)
#pragma unroll
        for (int ks = 0; ks < 2; ++ks)
          acc[mi][ni + 2] = __builtin_amdgcn_mfma_f32_16x16x32_bf16(
              af[mi][ks], bf_[ni][ks], acc[mi][ni + 2], 0, 0, 0);
    __builtin_amdgcn_s_setprio(0);

    if (t + 1 < NT) {
      asm volatile("s_waitcnt vmcnt(0)" ::: "memory");
      __syncthreads();
    }
  }

#pragma unroll
  for (int ni = 0; ni < 4; ++ni) {
    int col = o0 + wc * 64 + ni * 16 + lr;
    float bb = bias[col];
#pragma unroll
    for (int mi = 0; mi < 4; ++mi) {
      int row = i0 + wr * 64 + mi * 16 + lg * 4;
#pragma unroll
      for (int r = 0; r < 4; ++r)
        C[(size_t)(row + r) * DM + col] = (OUT_T)(acc[mi][ni][r] + bb);
    }
  }
}

// Output GEMM: grid 256 = 64 mi * 4 ni (exactly 1 block/CU), XCD-grouped.
__global__ __launch_bounds__(512, 2) void gemm_out_kernel(
    const __bf16* __restrict__ A, const __bf16* __restrict__ W,
    const float* __restrict__ bias, float* __restrict__ C) {
  __shared__ __align__(16) __bf16 lA[2 * 128 * 64];
  __shared__ __align__(16) __bf16 lB[2 * 256 * 64];
  const int flat = blockIdx.x;
  const int xcd = flat & 7, idx = flat >> 3;       // idx 0..31
  const int mi = xcd * 8 + (idx & 7);              // 0..63
  const int ni = idx >> 3;                         // 0..3
  gemm_body2<float>(A, W, bias, C, mi * 128, ni * 256, lA, lB);
}

// ---------------- pass B (FUSED-Q): both kt {31-bx, bx} share one Q stream ----------------
__global__ __launch_bounds__(256) void colstats_kernel(
    const __bf16* __restrict__ Q, const __bf16* __restrict__ K,
    const __bf16* __restrict__ V, __bf16* __restrict__ VT) {
  const int flat = blockIdx.x;
  const int wid = (flat & 7) * 128 + (flat >> 3);  // 0..1023
  const int g = wid >> 4, bx = wid & 15;
  const int h = g & 15, b = g >> 4;
  const int tid = threadIdx.x;
  const int w = tid >> 6, l = tid & 63, lr = l & 15, lg = l >> 4;
  const size_t base = (size_t)b * TSEQ * DM + (size_t)h * HD;

  const int kt1 = 31 - bx, kt2 = bx;
  const int k01 = kt1 * 64, k02 = kt2 * 64;

  __shared__ float part[4][64];
  __shared__ float invc[64];

  bf16x8 kf1[4][2], kf2[4][2];
#pragma unroll
  for (int ct = 0; ct < 4; ++ct)
#pragma unroll
    for (int ks = 0; ks < 2; ++ks) {
      kf1[ct][ks] = *(const bf16x8*)(K + base + (size_t)(k01 + ct * 16 + lr) * DM +
                                     ks * 32 + lg * 8);
      kf2[ct][ks] = *(const bf16x8*)(K + base + (size_t)(k02 + ct * 16 + lr) * DM +
                                     ks * 32 + lg * 8);
    }

  float csum1[4] = {0.f, 0.f, 0.f, 0.f};
  float csum2[4] = {0.f, 0.f, 0.f, 0.f};
  const int nchunks = (TSEQ - k02) >> 4;   // kt2's (larger) range
  for (int jj = w; jj < nchunks; jj += 4) {
    const int qrow = k02 + jj * 16;
    bf16x8 a0 = *(const bf16x8*)(Q + base + (size_t)(qrow + lr) * DM + lg * 8);
    bf16x8 a1 = *(const bf16x8*)(Q + base + (size_t)(qrow + lr) * DM + 32 + lg * 8);

    {
      const bool interior = (jj >= 4);
#pragma unroll
      for (int ct = 0; ct < 4; ++ct) {
        f32x4 s = {0.f, 0.f, 0.f, 0.f};
        s = __builtin_amdgcn_mfma_f32_16x16x32_bf16(a0, kf2[ct][0], s, 0, 0, 0);
        s = __builtin_amdgcn_mfma_f32_16x16x32_bf16(a1, kf2[ct][1], s, 0, 0, 0);
        if (interior) {
#pragma unroll
          for (int r = 0; r < 4; ++r) csum2[ct] += __builtin_amdgcn_exp2f(s[r] * SCL);
        } else {
#pragma unroll
          for (int r = 0; r < 4; ++r) {
            int ql = jj * 16 + lg * 4 + r;
            int kl = ct * 16 + lr;
            float e = __builtin_amdgcn_exp2f(s[r] * SCL);
            csum2[ct] += (ql >= kl) ? e : 0.f;
          }
        }
      }
    }
    if (qrow >= k01) {
      const bool interior = (qrow >= k01 + 64);
#pragma unroll
      for (int ct = 0; ct < 4; ++ct) {
        f32x4 s = {0.f, 0.f, 0.f, 0.f};
        s = __builtin_amdgcn_mfma_f32_16x16x32_bf16(a0, kf1[ct][0], s, 0, 0, 0);
        s = __builtin_amdgcn_mfma_f32_16x16x32_bf16(a1, kf1[ct][1], s, 0, 0, 0);
        if (interior) {
#pragma unroll
          for (int r = 0; r < 4; ++r) csum1[ct] += __builtin_amdgcn_exp2f(s[r] * SCL);
        } else {
#pragma unroll
          for (int r = 0; r < 4; ++r) {
            int ql = (qrow - k01) + lg * 4 + r;
            int kl = ct * 16 + lr;
            float e = __builtin_amdgcn_exp2f(s[r] * SCL);
            csum1[ct] += (ql >= kl) ? e : 0.f;
          }
        }
      }
    }
  }

#pragma unroll
  for (int ct = 0; ct < 4; ++ct) {
    csum1[ct] += __shfl_xor(csum1[ct], 16, 64);
    csum1[ct] += __shfl_xor(csum1[ct], 32, 64);
    csum2[ct] += __shfl_xor(csum2[ct], 16, 64);
    csum2[ct] += __shfl_xor(csum2[ct], 32, 64);
  }

  const int d = tid >> 2, gq = tid & 3;
  if (l < 16) {
#pragma unroll
    for (int ct = 0; ct < 4; ++ct) part[w][ct * 16 + l] = csum1[ct];
  }
  __syncthreads();
  if (tid < 64)
    invc[tid] = 1.0f / (part[0][tid] + part[1][tid] + part[2][tid] + part[3][tid]);
  __syncthreads();
  {
    size_t vtb = (((size_t)(b * NH + h)) * HD + d) * TSEQ + k01 + gq * 16;
#pragma unroll
    for (int kc = 0; kc < 16; kc += 2) {
      int kl = gq * 16 + kc;
      float v0 = (float)V[base + (size_t)(k01 + kl) * DM + d] * invc[kl];
      float v1 = (float)V[base + (size_t)(k01 + kl + 1) * DM + d] * invc[kl + 1];
      bf16x2 o; o[0] = (__bf16)v0; o[1] = (__bf16)v1;
      *(bf16x2*)(VT + vtb + kc) = o;
    }
  }
  __syncthreads();  // invc reads done before overwrite
  if (l < 16) {
#pragma unroll
    for (int ct = 0; ct < 4; ++ct) part[w][ct * 16 + l] = csum2[ct];
  }
  __syncthreads();
  if (tid < 64)
    invc[tid] = 1.0f / (part[0][tid] + part[1][tid] + part[2][tid] + part[3][tid]);
  __syncthreads();
  {
    size_t vtb = (((size_t)(b * NH + h)) * HD + d) * TSEQ + k02 + gq * 16;
#pragma unroll
    for (int kc = 0; kc < 16; kc += 2) {
      int kl = gq * 16 + kc;
      float v0 = (float)V[base + (size_t)(k02 + kl) * DM + d] * invc[kl];
      float v1 = (float)V[base + (size_t)(k02 + kl + 1) * DM + d] * invc[kl + 1];
      bf16x2 o; o[0] = (__bf16)v0; o[1] = (__bf16)v1;
      *(bf16x2*)(VT + vtb + kc) = o;
    }
  }
}

// XOR swizzle (involution) on element index of a [64][64] bf16 tile
__device__ __forceinline__ int swz(int e) { return e ^ (((e >> 6) & 7) << 3); }

// ---------------- pass C (FUSED x2): q-tiles {31-bx, bx} in ONE K-loop ----------------
__global__ __launch_bounds__(256, 4) void ctx_kernel(
    const __bf16* __restrict__ Q, const __bf16* __restrict__ K,
    const __bf16* __restrict__ VT, __bf16* __restrict__ CTX) {
  __shared__ __align__(16) __bf16 lK[4096];
  __shared__ __align__(16) __bf16 lV[4096];
  __shared__ __align__(16) __bf16 lP[8][16 * 88];   // [wave + 4*tile]
  const int flat = blockIdx.x;
  const int wid = (flat & 7) * 128 + (flat >> 3);  // 0..1023
  const int g = wid >> 4, bx = wid & 15;
  const int h = g & 15, b = g >> 4;
  const int tid = threadIdx.x;
  const int w = tid >> 6, l = tid & 63, lr = l & 15, lg = l >> 4;
  const size_t base = (size_t)b * TSEQ * DM + (size_t)h * HD;
  const size_t vtb = ((size_t)(b * NH + h)) * HD * TSEQ;
  __bf16* pw1 = &lP[w][0];
  __bf16* pw2 = &lP[w + 4][0];

  const int qt1 = 31 - bx, qt2 = bx;   // qt1 >= 16 > qt2 always
  const int q01 = qt1 * 64, q02 = qt2 * 64;

  const int srow = w * 8 + (l >> 3);
  const int scol = (((l & 7) ^ (l >> 3)) << 3);

  bf16x8 qf1[2], qf2[2];
#pragma unroll
  for (int ks = 0; ks < 2; ++ks) {
    qf1[ks] = *(const bf16x8*)(Q + base + (size_t)(q01 + w * 16 + lr) * DM + ks * 32 + lg * 8);
    qf2[ks] = *(const bf16x8*)(Q + base + (size_t)(q02 + w * 16 + lr) * DM + ks * 32 + lg * 8);
  }

  f32x4 acc1[4], acc2[4];
  const f32x4 fzero = {0.f, 0.f, 0.f, 0.f};
#pragma unroll
  for (int dt = 0; dt < 4; ++dt) { acc1[dt] = fzero; acc2[dt] = fzero; }

  for (int kt = 0; kt <= qt1; ++kt) {
    const int k0 = kt * 64;
    const bool two = (kt <= qt2);
    __syncthreads();   // prior iter's LDS reads done before overwrite
#pragma unroll
    for (int n = 0; n < 2; ++n) {
      gload16(K + base + (size_t)(k0 + n * 32 + srow) * DM + scol,
              lK + n * 2048 + w * 512);
      gload16(VT + vtb + (size_t)(n * 32 + srow) * TSEQ + k0 + scol,
              lV + n * 2048 + w * 512);
    }
    asm volatile("s_waitcnt vmcnt(0)" ::: "memory");
    __syncthreads();

    const bool diag1 = (kt == qt1), diag2 = (kt == qt2);
#pragma unroll
    for (int ct = 0; ct < 4; ++ct) {
      bf16x8 kb[2];
#pragma unroll
      for (int ks = 0; ks < 2; ++ks) {
        int e = (ct * 16 + lr) * 64 + ks * 32 + lg * 8;
        kb[ks] = *(const bf16x8*)(lK + swz(e));
      }
      {
        f32x4 s = {0.f, 0.f, 0.f, 0.f};
        s = __builtin_amdgcn_mfma_f32_16x16x32_bf16(kb[0], qf1[0], s, 0, 0, 0);
        s = __builtin_amdgcn_mfma_f32_16x16x32_bf16(kb[1], qf1[1], s, 0, 0, 0);
        bf16x4 pk;
        if (diag1) {
#pragma unroll
          for (int r = 0; r < 4; ++r) {
            int ql = w * 16 + lr, kl = ct * 16 + lg * 4 + r;
            pk[r] = (__bf16)((ql >= kl) ? __builtin_amdgcn_exp2f(s[r] * SCL) : 0.f);
          }
        } else {
#pragma unroll
          for (int r = 0; r < 4; ++r)
            pk[r] = (__bf16)__builtin_amdgcn_exp2f(s[r] * SCL);
        }
        *(bf16x4*)(pw1 + lr * 88 + ct * 16 + lg * 4) = pk;
      }
      if (two) {
        f32x4 s = {0.f, 0.f, 0.f, 0.f};
        s = __builtin_amdgcn_mfma_f32_16x16x32_bf16(kb[0], qf2[0], s, 0, 0, 0);
        s = __builtin_amdgcn_mfma_f32_16x16x32_bf16(kb[1], qf2[1], s, 0, 0, 0);
        bf16x4 pk;
        if (diag2) {
#pragma unroll
          for (int r = 0; r < 4; ++r) {
            int ql = w * 16 + lr, kl = ct * 16 + lg * 4 + r;
            pk[r] = (__bf16)((ql >= kl) ? __builtin_amdgcn_exp2f(s[r] * SCL) : 0.f);
          }
        } else {
#pragma unroll
          for (int r = 0; r < 4; ++r)
            pk[r] = (__bf16)__builtin_amdgcn_exp2f(s[r] * SCL);
        }
        *(bf16x4*)(pw2 + lr * 88 + ct * 16 + lg * 4) = pk;
      }
    }
    asm volatile("" ::: "memory");  // same-wave DS in-order: P writes before reads

    bf16x8 pa1[2], pa2[2];
#pragma unroll
    for (int ks = 0; ks < 2; ++ks)
      pa1[ks] = *(const bf16x8*)(pw1 + lr * 88 + ks * 32 + lg * 8);
    if (two) {
#pragma unroll
      for (int ks = 0; ks < 2; ++ks)
        pa2[ks] = *(const bf16x8*)(pw2 + lr * 88 + ks * 32 + lg * 8);
    }
#pragma unroll
    for (int dt = 0; dt < 4; ++dt) {
#pragma unroll
      for (int ks = 0; ks < 2; ++ks) {
        int e = (dt * 16 + lr) * 64 + ks * 32 + lg * 8;
        bf16x8 vb8 = *(const bf16x8*)(lV + swz(e));   // shared by both tiles
        acc1[dt] = __builtin_amdgcn_mfma_f32_16x16x32_bf16(pa1[ks], vb8, acc1[dt], 0, 0, 0);
        if (two)
          acc2[dt] = __builtin_amdgcn_mfma_f32_16x16x32_bf16(pa2[ks], vb8, acc2[dt], 0, 0, 0);
      }
    }
  }

#pragma unroll
  for (int dt = 0; dt < 4; ++dt)
#pragma unroll
    for (int r = 0; r < 4; ++r) {
      CTX[base + (size_t)(q01 + w * 16 + lg * 4 + r) * DM + dt * 16 + lr] = (__bf16)acc1[dt][r];
      CTX[base + (size_t)(q02 + w * 16 + lg * 4 + r) * DM + dt * 16 + lr] = (__bf16)acc2[dt][r];
    }
}

extern "C" void kernel_launch(void* const* d_in, const int* in_sizes, int n_in,
                              void* d_out, int out_size, void* d_ws, size_t ws_size,
                              hipStream_t stream) {
  const float* q  = (const float*)d_in[0];
  const float* Wq = (const float*)d_in[3];
  const float* bq = (const float*)d_in[4];
  const float* Wk = (const float*)d_in[5];
  const float* bk = (const float*)d_in[6];
  const float* Wv = (const float*)d_in[7];
  const float* bv = (const float*)d_in[8];
  const float* Wo = (const float*)d_in[9];
  const float* bo = (const float*)d_in[10];
  float* out = (float*)d_out;

  const size_t NTOK = (size_t)BATCH * TSEQ;  // 8192
  char* ws = (char*)d_ws;
  __bf16* qb   = (__bf16*)ws; ws += NTOK * DM * 2;      // reused as CTX later
  __bf16* Wqkv = (__bf16*)ws; ws += 3 * (size_t)DM * DM * 2;  // [3][1024][1024]
  __bf16* Wob  = (__bf16*)ws; ws += (size_t)DM * DM * 2;
  __bf16* QKVp = (__bf16*)ws; ws += 3 * NTOK * DM * 2;  // [3][8192][1024]
  __bf16* VT   = (__bf16*)ws; ws += (size_t)BATCH * NH * HD * TSEQ * 2;
  __bf16* CTX = qb;  // qb dead after the QKV GEMM

  __bf16* Qp = QKVp;
  __bf16* Kp = QKVp + NTOK * DM;
  __bf16* Vp = QKVp + 2 * NTOK * DM;

  const int nq4 = (int)(NTOK * DM / 4);
  const int nw4 = DM * DM / 4;
  cvt_kernel<<<(nq4 + 255) / 256, 256, 0, stream>>>(q, qb, nq4);
  cvt4_kernel<<<dim3((nw4 + 255) / 256, 4), 256, 0, stream>>>(
      Wq, Wk, Wv, Wo, Wqkv, Wqkv + (size_t)DM * DM, Wqkv + 2 * (size_t)DM * DM, Wob, nw4);

  gemm_qkv_kernel<<<512, 256, 0, stream>>>(qb, Wqkv, bq, bk, bv, QKVp);

  colstats_kernel<<<1024, 256, 0, stream>>>(Qp, Kp, Vp, VT);
  ctx_kernel<<<1024, 256, 0, stream>>>(Qp, Kp, VT, CTX);

  gemm_out_kernel<<<256, 512, 0, stream>>>(CTX, Wob, bo, out);
}

// Round 15
// 204.526 us; speedup vs baseline: 1.0439x; 1.0439x over previous
//
#include <hip/hip_runtime.h>
#include <hip/hip_bf16.h>
#include <cstdint>
#include <cstddef>

typedef __bf16 bf16x8 __attribute__((ext_vector_type(8)));
typedef __bf16 bf16x4 __attribute__((ext_vector_type(4)));
typedef __bf16 bf16x2 __attribute__((ext_vector_type(2)));
typedef float  f32x4  __attribute__((ext_vector_type(4)));

static constexpr int TSEQ  = 2048;
static constexpr int DM    = 1024;
static constexpr int NH    = 16;
static constexpr int HD    = 64;
static constexpr int BATCH = 4;
// exp(s/8) = 2^(s * log2(e)/8)
static constexpr float SCL = 0.18033688011112042f;

// async global->LDS, 16B per lane; LDS dest is wave-uniform base + lane*16
__device__ __forceinline__ void gload16(const __bf16* g, __bf16* l) {
  __builtin_amdgcn_global_load_lds((const __attribute__((address_space(1))) void*)g,
                                   (__attribute__((address_space(3))) void*)l, 16, 0, 0);
}

#define PBAR()  asm volatile("s_barrier" ::: "memory")
#define LGKM()  asm volatile("s_waitcnt lgkmcnt(0)" ::: "memory")

// ---------------- fp32 -> bf16 convert ----------------
__global__ __launch_bounds__(256) void cvt_kernel(const float* __restrict__ in,
                                                  __bf16* __restrict__ out, int n4) {
  int i = blockIdx.x * 256 + threadIdx.x;
  if (i < n4) {
    float4 v = reinterpret_cast<const float4*>(in)[i];
    bf16x4 o;
    o[0] = (__bf16)v.x; o[1] = (__bf16)v.y; o[2] = (__bf16)v.z; o[3] = (__bf16)v.w;
    reinterpret_cast<bf16x4*>(out)[i] = o;
  }
}

// 4 weight matrices in one launch (blockIdx.y selects)
__global__ __launch_bounds__(256) void cvt4_kernel(
    const float* __restrict__ a, const float* __restrict__ bsrc,
    const float* __restrict__ c, const float* __restrict__ d,
    __bf16* __restrict__ oa, __bf16* __restrict__ ob,
    __bf16* __restrict__ oc, __bf16* __restrict__ od, int n4) {
  const float* src = (blockIdx.y == 0) ? a : (blockIdx.y == 1) ? bsrc
                    : (blockIdx.y == 2) ? c : d;
  __bf16* dst = (blockIdx.y == 0) ? oa : (blockIdx.y == 1) ? ob
               : (blockIdx.y == 2) ? oc : od;
  int i = blockIdx.x * 256 + threadIdx.x;
  if (i < n4) {
    float4 v = reinterpret_cast<const float4*>(src)[i];
    bf16x4 o;
    o[0] = (__bf16)v.x; o[1] = (__bf16)v.y; o[2] = (__bf16)v.z; o[3] = (__bf16)v.w;
    reinterpret_cast<bf16x4*>(dst)[i] = o;
  }
}

// ---------------- QKV GEMM: 256x192, BK=64, 8 waves, R12 JIT-read 4-phase ----------------
// (best measured: 70.3 us, VGPR 104, no spill; R13 read-ahead and R14 4-wave
// variants both regressed -> this is the settled config)
__global__ __launch_bounds__(512, 2) void gemm_qkv_kernel(
    const __bf16* __restrict__ A, const __bf16* __restrict__ Wqkv,
    const float* __restrict__ b0, const float* __restrict__ b1,
    const float* __restrict__ b2, __bf16* __restrict__ QKVp) {
  __shared__ __align__(16) __bf16 lA[2 * 256 * 64];   // 64 KB
  __shared__ __align__(16) __bf16 lB[2 * 192 * 64];   // 48 KB
  const int flat = blockIdx.x;                 // 0..511
  const int xcd = flat & 7, idx = flat >> 3;   // idx 0..63
  const int mi = xcd * 4 + (idx & 3);          // 0..31
  const int nig = idx >> 2;                    // 0..15
  const int i0 = mi * 256, o0 = nig * 192;

  const int tid = threadIdx.x;
  const int l = tid & 63, lr = l & 15, lg = l >> 4;
  const int w = tid >> 6;
  const int wr = w >> 2, wc = w & 3;           // wave: rows wr*128, cols wc*48

  f32x4 acc[8][3];
  const f32x4 fzero = {0.f, 0.f, 0.f, 0.f};
#pragma unroll
  for (int mm = 0; mm < 8; ++mm)
#pragma unroll
    for (int ni = 0; ni < 3; ++ni) acc[mm][ni] = fzero;

  const int s_row = tid >> 3;                  // 0..63
  const int s_cc  = tid & 7;
  const __bf16* Ab = A + (size_t)i0 * DM;
  const __bf16* Wb = Wqkv + (size_t)o0 * DM;

  auto stageA = [&](int buf, int kt, int h) {
#pragma unroll
    for (int rr = 0; rr < 2; ++rr) {
      int row = h * 128 + rr * 64 + s_row;
      gload16(Ab + (size_t)row * DM + kt * 64 + ((s_cc ^ (row & 7)) << 3),
              lA + buf * 16384 + (h * 128 + rr * 64) * 64 + tid * 8);
    }
  };
  auto stageB = [&](int buf, int kt, int n) {
    int row = n * 64 + s_row;
    gload16(Wb + (size_t)row * DM + kt * 64 + ((s_cc ^ (row & 7)) << 3),
            lB + buf * 12288 + n * 4096 + tid * 8);
  };
  auto rdA = [&](const __bf16* base, int row, int ks) {
    int chunk = (ks * 4 + lg) ^ (row & 7);
    return *(const bf16x8*)(base + row * 64 + chunk * 8);
  };

  const int NT = DM / 64;                      // 16 K-tiles

  // prologue: tiles 0,1 staged (7 gloads each); vmcnt(7) -> tile 0 ready
#pragma unroll
  for (int h = 0; h < 2; ++h) stageA(0, 0, h);
#pragma unroll
  for (int n = 0; n < 3; ++n) stageB(0, 0, n);
#pragma unroll
  for (int h = 0; h < 2; ++h) stageA(1, 1, h);
#pragma unroll
  for (int n = 0; n < 3; ++n) stageB(1, 1, n);
  asm volatile("s_waitcnt vmcnt(7)" ::: "memory");
  PBAR();

  for (int t = 0; t < NT; ++t) {
    const int cur = t & 1;
    const __bf16* cA = lA + cur * 16384;
    const __bf16* cB = lB + cur * 12288;
    const bool pre = (t + 2 < NT);

    bf16x8 afl[4][2], afh[4][2], bfl[2][2], bfh[2];

    // ---- phase 1: Q1 = mi0-3 x ni0-1 (16 MFMA) ----
#pragma unroll
    for (int mm = 0; mm < 4; ++mm)
#pragma unroll
      for (int ks = 0; ks < 2; ++ks)
        afl[mm][ks] = rdA(cA, wr * 128 + mm * 16 + lr, ks);
#pragma unroll
    for (int ni = 0; ni < 2; ++ni)
#pragma unroll
      for (int ks = 0; ks < 2; ++ks)
        bfl[ni][ks] = rdA(cB, wc * 48 + ni * 16 + lr, ks);
    PBAR(); LGKM();
    __builtin_amdgcn_s_setprio(1);
#pragma unroll
    for (int mm = 0; mm < 4; ++mm)
#pragma unroll
      for (int ni = 0; ni < 2; ++ni)
#pragma unroll
        for (int ks = 0; ks < 2; ++ks)
          acc[mm][ni] = __builtin_amdgcn_mfma_f32_16x16x32_bf16(
              afl[mm][ks], bfl[ni][ks], acc[mm][ni], 0, 0, 0);
    __builtin_amdgcn_s_setprio(0);
    PBAR();

    // ---- phase 2: Q2 = mi0-3 x ni2 (8 MFMA); stage B n0,n1 (t+2) ----
#pragma unroll
    for (int ks = 0; ks < 2; ++ks)
      bfh[ks] = rdA(cB, wc * 48 + 2 * 16 + lr, ks);
    if (pre) { stageB(cur, t + 2, 0); stageB(cur, t + 2, 1); }
    PBAR(); LGKM();
    __builtin_amdgcn_s_setprio(1);
#pragma unroll
    for (int mm = 0; mm < 4; ++mm)
#pragma unroll
      for (int ks = 0; ks < 2; ++ks)
        acc[mm][2] = __builtin_amdgcn_mfma_f32_16x16x32_bf16(
            afl[mm][ks], bfh[ks], acc[mm][2], 0, 0, 0);
    __builtin_amdgcn_s_setprio(0);
    PBAR();

    // ---- phase 3: Q3 = mi4-7 x ni0-1 (16 MFMA); stage B n2 + A h0 (t+2) ----
#pragma unroll
    for (int mm = 0; mm < 4; ++mm)
#pragma unroll
      for (int ks = 0; ks < 2; ++ks)
        afh[mm][ks] = rdA(cA, wr * 128 + (mm + 4) * 16 + lr, ks);
    if (pre) { stageB(cur, t + 2, 2); stageA(cur, t + 2, 0); }
    PBAR(); LGKM();
    __builtin_amdgcn_s_setprio(1);
#pragma unroll
    for (int mm = 0; mm < 4; ++mm)
#pragma unroll
      for (int ni = 0; ni < 2; ++ni)
#pragma unroll
        for (int ks = 0; ks < 2; ++ks)
          acc[mm + 4][ni] = __builtin_amdgcn_mfma_f32_16x16x32_bf16(
              afh[mm][ks], bfl[ni][ks], acc[mm + 4][ni], 0, 0, 0);
    __builtin_amdgcn_s_setprio(0);
    PBAR();

    // ---- phase 4: Q4 = mi4-7 x ni2 (8 MFMA); stage A h1 (t+2); counted vmcnt ----
    if (pre) stageA(cur, t + 2, 1);
    if (pre)                asm volatile("s_waitcnt vmcnt(7)" ::: "memory");
    else if (t + 1 < NT)    asm volatile("s_waitcnt vmcnt(0)" ::: "memory");
    PBAR();
    __builtin_amdgcn_s_setprio(1);
#pragma unroll
    for (int mm = 0; mm < 4; ++mm)
#pragma unroll
      for (int ks = 0; ks < 2; ++ks)
        acc[mm + 4][2] = __builtin_amdgcn_mfma_f32_16x16x32_bf16(
            afh[mm][ks], bfh[ks], acc[mm + 4][2], 0, 0, 0);
    __builtin_amdgcn_s_setprio(0);
    PBAR();
  }

#pragma unroll
  for (int ni = 0; ni < 3; ++ni) {
    int col = o0 + wc * 48 + ni * 16 + lr;     // global col in [0,3072)
    int z = col >> 10, cin = col & 1023;       // uniform z per 16-col group
    const float* bp = (z == 0) ? b0 : (z == 1) ? b1 : b2;
    float bb = bp[cin];
    __bf16* O = QKVp + (size_t)z * 8192 * DM;
#pragma unroll
    for (int mm = 0; mm < 8; ++mm) {
      int row = i0 + wr * 128 + mm * 16 + lg * 4;
#pragma unroll
      for (int r = 0; r < 4; ++r)
        O[(size_t)(row + r) * DM + cin] = (__bf16)(acc[mm][ni][r] + bb);
    }
  }
}

// ---------------- out-proj GEMM: 128x256, BK=64, 8 waves, 4-phase counted-vmcnt ----------------
// R6-proven structure scaled to 128x256: wave output = 4 scattered 32x32 strips
// (rows {wr*32, 64+wr*32} x cols {wc*32, 128+wc*32}) so each phase's reads
// localize to one A/B half-slot -> slots free mid-tile, stages stream 1-2
// halves/phase, single vmcnt(6)/K-tile. LDS 96 KB dbuf; acc 64 AGPR.
__global__ __launch_bounds__(512, 2) void gemm_out_kernel(
    const __bf16* __restrict__ A, const __bf16* __restrict__ W,
    const float* __restrict__ bias, float* __restrict__ C) {
  __shared__ __align__(16) __bf16 lA[2 * 128 * 64];   // 32 KB
  __shared__ __align__(16) __bf16 lB[2 * 256 * 64];   // 64 KB
  const int flat = blockIdx.x;                 // 0..255
  const int xcd = flat & 7, idx = flat >> 3;   // idx 0..31
  const int mi = xcd * 8 + (idx & 7);          // 0..63
  const int nig = idx >> 3;                    // 0..3
  const int i0 = mi * 128, o0 = nig * 256;

  const int tid = threadIdx.x;
  const int l = tid & 63, lr = l & 15, lg = l >> 4;
  const int w = tid >> 6;
  const int wr = w >> 2, wc = w & 3;

  f32x4 acc[4][4];
  const f32x4 fzero = {0.f, 0.f, 0.f, 0.f};
#pragma unroll
  for (int mm = 0; mm < 4; ++mm)
#pragma unroll
    for (int ni = 0; ni < 4; ++ni) acc[mm][ni] = fzero;

  const int s_row = tid >> 3;                  // 0..63
  const int s_cc  = tid & 7;
  const __bf16* Ab = A + (size_t)i0 * DM;
  const __bf16* Wb = W + (size_t)o0 * DM;

  auto stageA = [&](int buf, int kt, int h) {  // A half = 64 rows = 1 gload
    int row = h * 64 + s_row;
    gload16(Ab + (size_t)row * DM + kt * 64 + ((s_cc ^ (row & 7)) << 3),
            lA + buf * 8192 + h * 4096 + tid * 8);
  };
  auto stageB = [&](int buf, int kt, int h) {  // B half = 128 rows = 2 gloads
#pragma unroll
    for (int rr = 0; rr < 2; ++rr) {
      int row = h * 128 + rr * 64 + s_row;
      gload16(Wb + (size_t)row * DM + kt * 64 + ((s_cc ^ (row & 7)) << 3),
              lB + buf * 16384 + (h * 128 + rr * 64) * 64 + tid * 8);
    }
  };
  auto rd = [&](const __bf16* base, int row, int ks) {
    int chunk = (ks * 4 + lg) ^ (row & 7);
    return *(const bf16x8*)(base + row * 64 + chunk * 8);
  };

  const int NT = DM / 64;                      // 16

  // prologue: tiles 0,1 staged (6 gloads each); vmcnt(6) -> tile 0 ready
#pragma unroll
  for (int h = 0; h < 2; ++h) { stageA(0, 0, h); stageB(0, 0, h); }
#pragma unroll
  for (int h = 0; h < 2; ++h) { stageA(1, 1, h); stageB(1, 1, h); }
  asm volatile("s_waitcnt vmcnt(6)" ::: "memory");
  PBAR();

  for (int t = 0; t < NT; ++t) {
    const int cur = t & 1;
    const __bf16* cA = lA + cur * 8192;
    const __bf16* cB = lB + cur * 16384;
    const bool pre = (t + 2 < NT);

    bf16x8 afl[2][2], afh[2][2], bfl[2][2], bfh[2][2];

    // ---- phase 1: mi-lo x ni-lo (A-h0, B-h0 reads) ----
#pragma unroll
    for (int mm = 0; mm < 2; ++mm)
#pragma unroll
      for (int ks = 0; ks < 2; ++ks)
        afl[mm][ks] = rd(cA, wr * 32 + mm * 16 + lr, ks);
#pragma unroll
    for (int ni = 0; ni < 2; ++ni)
#pragma unroll
      for (int ks = 0; ks < 2; ++ks)
        bfl[ni][ks] = rd(cB, wc * 32 + ni * 16 + lr, ks);
    PBAR(); LGKM();
    __builtin_amdgcn_s_setprio(1);
#pragma unroll
    for (int mm = 0; mm < 2; ++mm)
#pragma unroll
      for (int ni = 0; ni < 2; ++ni)
#pragma unroll
        for (int ks = 0; ks < 2; ++ks)
          acc[mm][ni] = __builtin_amdgcn_mfma_f32_16x16x32_bf16(
              afl[mm][ks], bfl[ni][ks], acc[mm][ni], 0, 0, 0);
    __builtin_amdgcn_s_setprio(0);
    PBAR();

    // ---- phase 2: mi-lo x ni-hi (B-h1 reads); stage Bh0(t+2) ----
#pragma unroll
    for (int ni = 0; ni < 2; ++ni)
#pragma unroll
      for (int ks = 0; ks < 2; ++ks)
        bfh[ni][ks] = rd(cB, 128 + wc * 32 + ni * 16 + lr, ks);
    if (pre) stageB(cur, t + 2, 0);
    PBAR(); LGKM();
    __builtin_amdgcn_s_setprio(1);
#pragma unroll
    for (int mm = 0; mm < 2; ++mm)
#pragma unroll
      for (int ni = 0; ni < 2; ++ni)
#pragma unroll
        for (int ks = 0; ks < 2; ++ks)
          acc[mm][ni + 2] = __builtin_amdgcn_mfma_f32_16x16x32_bf16(
              afl[mm][ks], bfh[ni][ks], acc[mm][ni + 2], 0, 0, 0);
    __builtin_amdgcn_s_setprio(0);
    PBAR();

    // ---- phase 3: mi-hi x ni-lo (A-h1 reads); stage Ah0,Bh1(t+2) ----
#pragma unroll
    for (int mm = 0; mm < 2; ++mm)
#pragma unroll
      for (int ks = 0; ks < 2; ++ks)
        afh[mm][ks] = rd(cA, 64 + wr * 32 + mm * 16 + lr, ks);
    if (pre) { stageA(cur, t + 2, 0); stageB(cur, t + 2, 1); }
    PBAR(); LGKM();
    __builtin_amdgcn_s_setprio(1);
#pragma unroll
    for (int mm = 0; mm < 2; ++mm)
#pragma unroll
      for (int ni = 0; ni < 2; ++ni)
#pragma unroll
        for (int ks = 0; ks < 2; ++ks)
          acc[mm + 2][ni] = __builtin_amdgcn_mfma_f32_16x16x32_bf16(
              afh[mm][ks], bfl[ni][ks], acc[mm + 2][ni], 0, 0, 0);
    __builtin_amdgcn_s_setprio(0);
    PBAR();

    // ---- phase 4: mi-hi x ni-hi (held regs); stage Ah1(t+2); counted vmcnt ----
    if (pre) stageA(cur, t + 2, 1);
    if (pre)                asm volatile("s_waitcnt vmcnt(6)" ::: "memory");
    else if (t + 1 < NT)    asm volatile("s_waitcnt vmcnt(0)" ::: "memory");
    PBAR();
    __builtin_amdgcn_s_setprio(1);
#pragma unroll
    for (int mm = 0; mm < 2; ++mm)
#pragma unroll
      for (int ni = 0; ni < 2; ++ni)
#pragma unroll
        for (int ks = 0; ks < 2; ++ks)
          acc[mm + 2][ni + 2] = __builtin_amdgcn_mfma_f32_16x16x32_bf16(
              afh[mm][ks], bfh[ni][ks], acc[mm + 2][ni + 2], 0, 0, 0);
    __builtin_amdgcn_s_setprio(0);
    PBAR();
  }

#pragma unroll
  for (int ni = 0; ni < 4; ++ni) {
    int colb = (ni < 2) ? (wc * 32 + ni * 16) : (128 + wc * 32 + (ni - 2) * 16);
    int col = o0 + colb + lr;
    float bb = bias[col];
#pragma unroll
    for (int mm = 0; mm < 4; ++mm) {
      int rowb = (mm < 2) ? (wr * 32 + mm * 16) : (64 + wr * 32 + (mm - 2) * 16);
      int row = i0 + rowb + lg * 4;
#pragma unroll
      for (int r = 0; r < 4; ++r)
        C[(size_t)(row + r) * DM + col] = acc[mm][ni][r] + bb;
    }
  }
}

// ---------------- pass B (FUSED-Q): both kt {31-bx, bx} share one Q stream ----------------
__global__ __launch_bounds__(256) void colstats_kernel(
    const __bf16* __restrict__ Q, const __bf16* __restrict__ K,
    const __bf16* __restrict__ V, __bf16* __restrict__ VT) {
  const int flat = blockIdx.x;
  const int wid = (flat & 7) * 128 + (flat >> 3);  // 0..1023
  const int g = wid >> 4, bx = wid & 15;
  const int h = g & 15, b = g >> 4;
  const int tid = threadIdx.x;
  const int w = tid >> 6, l = tid & 63, lr = l & 15, lg = l >> 4;
  const size_t base = (size_t)b * TSEQ * DM + (size_t)h * HD;

  const int kt1 = 31 - bx, kt2 = bx;
  const int k01 = kt1 * 64, k02 = kt2 * 64;

  __shared__ float part[4][64];
  __shared__ float invc[64];

  bf16x8 kf1[4][2], kf2[4][2];
#pragma unroll
  for (int ct = 0; ct < 4; ++ct)
#pragma unroll
    for (int ks = 0; ks < 2; ++ks) {
      kf1[ct][ks] = *(const bf16x8*)(K + base + (size_t)(k01 + ct * 16 + lr) * DM +
                                     ks * 32 + lg * 8);
      kf2[ct][ks] = *(const bf16x8*)(K + base + (size_t)(k02 + ct * 16 + lr) * DM +
                                     ks * 32 + lg * 8);
    }

  float csum1[4] = {0.f, 0.f, 0.f, 0.f};
  float csum2[4] = {0.f, 0.f, 0.f, 0.f};
  const int nchunks = (TSEQ - k02) >> 4;   // kt2's (larger) range
  for (int jj = w; jj < nchunks; jj += 4) {
    const int qrow = k02 + jj * 16;
    bf16x8 a0 = *(const bf16x8*)(Q + base + (size_t)(qrow + lr) * DM + lg * 8);
    bf16x8 a1 = *(const bf16x8*)(Q + base + (size_t)(qrow + lr) * DM + 32 + lg * 8);

    {
      const bool interior = (jj >= 4);
#pragma unroll
      for (int ct = 0; ct < 4; ++ct) {
        f32x4 s = {0.f, 0.f, 0.f, 0.f};
        s = __builtin_amdgcn_mfma_f32_16x16x32_bf16(a0, kf2[ct][0], s, 0, 0, 0);
        s = __builtin_amdgcn_mfma_f32_16x16x32_bf16(a1, kf2[ct][1], s, 0, 0, 0);
        if (interior) {
#pragma unroll
          for (int r = 0; r < 4; ++r) csum2[ct] += __builtin_amdgcn_exp2f(s[r] * SCL);
        } else {
#pragma unroll
          for (int r = 0; r < 4; ++r) {
            int ql = jj * 16 + lg * 4 + r;
            int kl = ct * 16 + lr;
            float e = __builtin_amdgcn_exp2f(s[r] * SCL);
            csum2[ct] += (ql >= kl) ? e : 0.f;
          }
        }
      }
    }
    if (qrow >= k01) {
      const bool interior = (qrow >= k01 + 64);
#pragma unroll
      for (int ct = 0; ct < 4; ++ct) {
        f32x4 s = {0.f, 0.f, 0.f, 0.f};
        s = __builtin_amdgcn_mfma_f32_16x16x32_bf16(a0, kf1[ct][0], s, 0, 0, 0);
        s = __builtin_amdgcn_mfma_f32_16x16x32_bf16(a1, kf1[ct][1], s, 0, 0, 0);
        if (interior) {
#pragma unroll
          for (int r = 0; r < 4; ++r) csum1[ct] += __builtin_amdgcn_exp2f(s[r] * SCL);
        } else {
#pragma unroll
          for (int r = 0; r < 4; ++r) {
            int ql = (qrow - k01) + lg * 4 + r;
            int kl = ct * 16 + lr;
            float e = __builtin_amdgcn_exp2f(s[r] * SCL);
            csum1[ct] += (ql >= kl) ? e : 0.f;
          }
        }
      }
    }
  }

#pragma unroll
  for (int ct = 0; ct < 4; ++ct) {
    csum1[ct] += __shfl_xor(csum1[ct], 16, 64);
    csum1[ct] += __shfl_xor(csum1[ct], 32, 64);
    csum2[ct] += __shfl_xor(csum2[ct], 16, 64);
    csum2[ct] += __shfl_xor(csum2[ct], 32, 64);
  }

  const int d = tid >> 2, gq = tid & 3;
  if (l < 16) {
#pragma unroll
    for (int ct = 0; ct < 4; ++ct) part[w][ct * 16 + l] = csum1[ct];
  }
  __syncthreads();
  if (tid < 64)
    invc[tid] = 1.0f / (part[0][tid] + part[1][tid] + part[2][tid] + part[3][tid]);
  __syncthreads();
  {
    size_t vtb = (((size_t)(b * NH + h)) * HD + d) * TSEQ + k01 + gq * 16;
#pragma unroll
    for (int kc = 0; kc < 16; kc += 2) {
      int kl = gq * 16 + kc;
      float v0 = (float)V[base + (size_t)(k01 + kl) * DM + d] * invc[kl];
      float v1 = (float)V[base + (size_t)(k01 + kl + 1) * DM + d] * invc[kl + 1];
      bf16x2 o; o[0] = (__bf16)v0; o[1] = (__bf16)v1;
      *(bf16x2*)(VT + vtb + kc) = o;
    }
  }
  __syncthreads();  // invc reads done before overwrite
  if (l < 16) {
#pragma unroll
    for (int ct = 0; ct < 4; ++ct) part[w][ct * 16 + l] = csum2[ct];
  }
  __syncthreads();
  if (tid < 64)
    invc[tid] = 1.0f / (part[0][tid] + part[1][tid] + part[2][tid] + part[3][tid]);
  __syncthreads();
  {
    size_t vtb = (((size_t)(b * NH + h)) * HD + d) * TSEQ + k02 + gq * 16;
#pragma unroll
    for (int kc = 0; kc < 16; kc += 2) {
      int kl = gq * 16 + kc;
      float v0 = (float)V[base + (size_t)(k02 + kl) * DM + d] * invc[kl];
      float v1 = (float)V[base + (size_t)(k02 + kl + 1) * DM + d] * invc[kl + 1];
      bf16x2 o; o[0] = (__bf16)v0; o[1] = (__bf16)v1;
      *(bf16x2*)(VT + vtb + kc) = o;
    }
  }
}

// XOR swizzle (involution) on element index of a [64][64] bf16 tile
__device__ __forceinline__ int swz(int e) { return e ^ (((e >> 6) & 7) << 3); }

// ---------------- pass C (FUSED x2): q-tiles {31-bx, bx} in ONE K-loop ----------------
__global__ __launch_bounds__(256, 4) void ctx_kernel(
    const __bf16* __restrict__ Q, const __bf16* __restrict__ K,
    const __bf16* __restrict__ VT, __bf16* __restrict__ CTX) {
  __shared__ __align__(16) __bf16 lK[4096];
  __shared__ __align__(16) __bf16 lV[4096];
  __shared__ __align__(16) __bf16 lP[8][16 * 88];   // [wave + 4*tile]
  const int flat = blockIdx.x;
  const int wid = (flat & 7) * 128 + (flat >> 3);  // 0..1023
  const int g = wid >> 4, bx = wid & 15;
  const int h = g & 15, b = g >> 4;
  const int tid = threadIdx.x;
  const int w = tid >> 6, l = tid & 63, lr = l & 15, lg = l >> 4;
  const size_t base = (size_t)b * TSEQ * DM + (size_t)h * HD;
  const size_t vtb = ((size_t)(b * NH + h)) * HD * TSEQ;
  __bf16* pw1 = &lP[w][0];
  __bf16* pw2 = &lP[w + 4][0];

  const int qt1 = 31 - bx, qt2 = bx;   // qt1 >= 16 > qt2 always
  const int q01 = qt1 * 64, q02 = qt2 * 64;

  const int srow = w * 8 + (l >> 3);
  const int scol = (((l & 7) ^ (l >> 3)) << 3);

  bf16x8 qf1[2], qf2[2];
#pragma unroll
  for (int ks = 0; ks < 2; ++ks) {
    qf1[ks] = *(const bf16x8*)(Q + base + (size_t)(q01 + w * 16 + lr) * DM + ks * 32 + lg * 8);
    qf2[ks] = *(const bf16x8*)(Q + base + (size_t)(q02 + w * 16 + lr) * DM + ks * 32 + lg * 8);
  }

  f32x4 acc1[4], acc2[4];
  const f32x4 fzero = {0.f, 0.f, 0.f, 0.f};
#pragma unroll
  for (int dt = 0; dt < 4; ++dt) { acc1[dt] = fzero; acc2[dt] = fzero; }

  for (int kt = 0; kt <= qt1; ++kt) {
    const int k0 = kt * 64;
    const bool two = (kt <= qt2);
    __syncthreads();   // prior iter's LDS reads done before overwrite
#pragma unroll
    for (int n = 0; n < 2; ++n) {
      gload16(K + base + (size_t)(k0 + n * 32 + srow) * DM + scol,
              lK + n * 2048 + w * 512);
      gload16(VT + vtb + (size_t)(n * 32 + srow) * TSEQ + k0 + scol,
              lV + n * 2048 + w * 512);
    }
    asm volatile("s_waitcnt vmcnt(0)" ::: "memory");
    __syncthreads();

    const bool diag1 = (kt == qt1), diag2 = (kt == qt2);
#pragma unroll
    for (int ct = 0; ct < 4; ++ct) {
      bf16x8 kb[2];
#pragma unroll
      for (int ks = 0; ks < 2; ++ks) {
        int e = (ct * 16 + lr) * 64 + ks * 32 + lg * 8;
        kb[ks] = *(const bf16x8*)(lK + swz(e));
      }
      {
        f32x4 s = {0.f, 0.f, 0.f, 0.f};
        s = __builtin_amdgcn_mfma_f32_16x16x32_bf16(kb[0], qf1[0], s, 0, 0, 0);
        s = __builtin_amdgcn_mfma_f32_16x16x32_bf16(kb[1], qf1[1], s, 0, 0, 0);
        bf16x4 pk;
        if (diag1) {
#pragma unroll
          for (int r = 0; r < 4; ++r) {
            int ql = w * 16 + lr, kl = ct * 16 + lg * 4 + r;
            pk[r] = (__bf16)((ql >= kl) ? __builtin_amdgcn_exp2f(s[r] * SCL) : 0.f);
          }
        } else {
#pragma unroll
          for (int r = 0; r < 4; ++r)
            pk[r] = (__bf16)__builtin_amdgcn_exp2f(s[r] * SCL);
        }
        *(bf16x4*)(pw1 + lr * 88 + ct * 16 + lg * 4) = pk;
      }
      if (two) {
        f32x4 s = {0.f, 0.f, 0.f, 0.f};
        s = __builtin_amdgcn_mfma_f32_16x16x32_bf16(kb[0], qf2[0], s, 0, 0, 0);
        s = __builtin_amdgcn_mfma_f32_16x16x32_bf16(kb[1], qf2[1], s, 0, 0, 0);
        bf16x4 pk;
        if (diag2) {
#pragma unroll
          for (int r = 0; r < 4; ++r) {
            int ql = w * 16 + lr, kl = ct * 16 + lg * 4 + r;
            pk[r] = (__bf16)((ql >= kl) ? __builtin_amdgcn_exp2f(s[r] * SCL) : 0.f);
          }
        } else {
#pragma unroll
          for (int r = 0; r < 4; ++r)
            pk[r] = (__bf16)__builtin_amdgcn_exp2f(s[r] * SCL);
        }
        *(bf16x4*)(pw2 + lr * 88 + ct * 16 + lg * 4) = pk;
      }
    }
    asm volatile("" ::: "memory");  // same-wave DS in-order: P writes before reads

    bf16x8 pa1[2], pa2[2];
#pragma unroll
    for (int ks = 0; ks < 2; ++ks)
      pa1[ks] = *(const bf16x8*)(pw1 + lr * 88 + ks * 32 + lg * 8);
    if (two) {
#pragma unroll
      for (int ks = 0; ks < 2; ++ks)
        pa2[ks] = *(const bf16x8*)(pw2 + lr * 88 + ks * 32 + lg * 8);
    }
#pragma unroll
    for (int dt = 0; dt < 4; ++dt) {
#pragma unroll
      for (int ks = 0; ks < 2; ++ks) {
        int e = (dt * 16 + lr) * 64 + ks * 32 + lg * 8;
        bf16x8 vb8 = *(const bf16x8*)(lV + swz(e));   // shared by both tiles
        acc1[dt] = __builtin_amdgcn_mfma_f32_16x16x32_bf16(pa1[ks], vb8, acc1[dt], 0, 0, 0);
        if (two)
          acc2[dt] = __builtin_amdgcn_mfma_f32_16x16x32_bf16(pa2[ks], vb8, acc2[dt], 0, 0, 0);
      }
    }
  }

#pragma unroll
  for (int dt = 0; dt < 4; ++dt)
#pragma unroll
    for (int r = 0; r < 4; ++r) {
      CTX[base + (size_t)(q01 + w * 16 + lg * 4 + r) * DM + dt * 16 + lr] = (__bf16)acc1[dt][r];
      CTX[base + (size_t)(q02 + w * 16 + lg * 4 + r) * DM + dt * 16 + lr] = (__bf16)acc2[dt][r];
    }
}

extern "C" void kernel_launch(void* const* d_in, const int* in_sizes, int n_in,
                              void* d_out, int out_size, void* d_ws, size_t ws_size,
                              hipStream_t stream) {
  const float* q  = (const float*)d_in[0];
  const float* Wq = (const float*)d_in[3];
  const float* bq = (const float*)d_in[4];
  const float* Wk = (const float*)d_in[5];
  const float* bk = (const float*)d_in[6];
  const float* Wv = (const float*)d_in[7];
  const float* bv = (const float*)d_in[8];
  const float* Wo = (const float*)d_in[9];
  const float* bo = (const float*)d_in[10];
  float* out = (float*)d_out;

  const size_t NTOK = (size_t)BATCH * TSEQ;  // 8192
  char* ws = (char*)d_ws;
  __bf16* qb   = (__bf16*)ws; ws += NTOK * DM * 2;      // reused as CTX later
  __bf16* Wqkv = (__bf16*)ws; ws += 3 * (size_t)DM * DM * 2;  // [3][1024][1024]
  __bf16* Wob  = (__bf16*)ws; ws += (size_t)DM * DM * 2;
  __bf16* QKVp = (__bf16*)ws; ws += 3 * NTOK * DM * 2;  // [3][8192][1024]
  __bf16* VT   = (__bf16*)ws; ws += (size_t)BATCH * NH * HD * TSEQ * 2;
  __bf16* CTX = qb;  // qb dead after the QKV GEMM

  __bf16* Qp = QKVp;
  __bf16* Kp = QKVp + NTOK * DM;
  __bf16* Vp = QKVp + 2 * NTOK * DM;

  const int nq4 = (int)(NTOK * DM / 4);
  const int nw4 = DM * DM / 4;
  cvt_kernel<<<(nq4 + 255) / 256, 256, 0, stream>>>(q, qb, nq4);
  cvt4_kernel<<<dim3((nw4 + 255) / 256, 4), 256, 0, stream>>>(
      Wq, Wk, Wv, Wo, Wqkv, Wqkv + (size_t)DM * DM, Wqkv + 2 * (size_t)DM * DM, Wob, nw4);

  gemm_qkv_kernel<<<512, 512, 0, stream>>>(qb, Wqkv, bq, bk, bv, QKVp);

  colstats_kernel<<<1024, 256, 0, stream>>>(Qp, Kp, Vp, VT);
  ctx_kernel<<<1024, 256, 0, stream>>>(Qp, Kp, VT, CTX);

  gemm_out_kernel<<<256, 512, 0, stream>>>(CTX, Wob, bo, out);
}

// Round 16
// 202.293 us; speedup vs baseline: 1.0555x; 1.0110x over previous
//
#include <hip/hip_runtime.h>
#include <hip/hip_bf16.h>
#include <cstdint>
#include <cstddef>

typedef __bf16 bf16x8 __attribute__((ext_vector_type(8)));
typedef __bf16 bf16x4 __attribute__((ext_vector_type(4)));
typedef __bf16 bf16x2 __attribute__((ext_vector_type(2)));
typedef float  f32x4  __attribute__((ext_vector_type(4)));

static constexpr int TSEQ  = 2048;
static constexpr int DM    = 1024;
static constexpr int NH    = 16;
static constexpr int HD    = 64;
static constexpr int BATCH = 4;
// exp(s/8) = 2^(s * log2(e)/8)
static constexpr float SCL = 0.18033688011112042f;

// async global->LDS, 16B per lane; LDS dest is wave-uniform base + lane*16
__device__ __forceinline__ void gload16(const __bf16* g, __bf16* l) {
  __builtin_amdgcn_global_load_lds((const __attribute__((address_space(1))) void*)g,
                                   (__attribute__((address_space(3))) void*)l, 16, 0, 0);
}

#define PBAR()  asm volatile("s_barrier" ::: "memory")
#define LGKM()  asm volatile("s_waitcnt lgkmcnt(0)" ::: "memory")

// ---------------- fused fp32 -> bf16 convert (q + all 4 weights, ONE launch) ----------------
// flat f4 index space: [0, NQ4) -> q->qb ; [NQ4, NQ4+4*NW4) -> {Wq,Wk,Wv,Wo} ->
// contiguous {Wqkv[0..2], Wob} (dest regions are contiguous in ws).
__global__ __launch_bounds__(256) void cvt_all_kernel(
    const float* __restrict__ q, const float* __restrict__ Wq,
    const float* __restrict__ Wk, const float* __restrict__ Wv,
    const float* __restrict__ Wo,
    __bf16* __restrict__ qb, __bf16* __restrict__ Wqkv_and_Wob,
    int nq4, int nw4) {
  int i = blockIdx.x * 256 + threadIdx.x;
  const float* src;
  __bf16* dst;
  int off;
  if (i < nq4) {
    src = q; dst = qb; off = i;
  } else {
    int j = i - nq4;
    int sel = j / nw4;              // 0..3
    off = j - sel * nw4;
    src = (sel == 0) ? Wq : (sel == 1) ? Wk : (sel == 2) ? Wv : Wo;
    dst = Wqkv_and_Wob + (size_t)sel * (size_t)DM * DM;
  }
  float4 v = reinterpret_cast<const float4*>(src)[off];
  bf16x4 o;
  o[0] = (__bf16)v.x; o[1] = (__bf16)v.y; o[2] = (__bf16)v.z; o[3] = (__bf16)v.w;
  reinterpret_cast<bf16x4*>(dst)[off] = o;
}

// ---------------- QKV GEMM: 256x192, BK=64, 8 waves, R12 JIT-read 4-phase ----------------
// (settled best: ~70 us, VGPR 104, no spill)
__global__ __launch_bounds__(512, 2) void gemm_qkv_kernel(
    const __bf16* __restrict__ A, const __bf16* __restrict__ Wqkv,
    const float* __restrict__ b0, const float* __restrict__ b1,
    const float* __restrict__ b2, __bf16* __restrict__ QKVp) {
  __shared__ __align__(16) __bf16 lA[2 * 256 * 64];   // 64 KB
  __shared__ __align__(16) __bf16 lB[2 * 192 * 64];   // 48 KB
  const int flat = blockIdx.x;                 // 0..511
  const int xcd = flat & 7, idx = flat >> 3;   // idx 0..63
  const int mi = xcd * 4 + (idx & 3);          // 0..31
  const int nig = idx >> 2;                    // 0..15
  const int i0 = mi * 256, o0 = nig * 192;

  const int tid = threadIdx.x;
  const int l = tid & 63, lr = l & 15, lg = l >> 4;
  const int w = tid >> 6;
  const int wr = w >> 2, wc = w & 3;           // wave: rows wr*128, cols wc*48

  f32x4 acc[8][3];
  const f32x4 fzero = {0.f, 0.f, 0.f, 0.f};
#pragma unroll
  for (int mm = 0; mm < 8; ++mm)
#pragma unroll
    for (int ni = 0; ni < 3; ++ni) acc[mm][ni] = fzero;

  const int s_row = tid >> 3;                  // 0..63
  const int s_cc  = tid & 7;
  const __bf16* Ab = A + (size_t)i0 * DM;
  const __bf16* Wb = Wqkv + (size_t)o0 * DM;

  auto stageA = [&](int buf, int kt, int h) {
#pragma unroll
    for (int rr = 0; rr < 2; ++rr) {
      int row = h * 128 + rr * 64 + s_row;
      gload16(Ab + (size_t)row * DM + kt * 64 + ((s_cc ^ (row & 7)) << 3),
              lA + buf * 16384 + (h * 128 + rr * 64) * 64 + tid * 8);
    }
  };
  auto stageB = [&](int buf, int kt, int n) {
    int row = n * 64 + s_row;
    gload16(Wb + (size_t)row * DM + kt * 64 + ((s_cc ^ (row & 7)) << 3),
            lB + buf * 12288 + n * 4096 + tid * 8);
  };
  auto rdA = [&](const __bf16* base, int row, int ks) {
    int chunk = (ks * 4 + lg) ^ (row & 7);
    return *(const bf16x8*)(base + row * 64 + chunk * 8);
  };

  const int NT = DM / 64;                      // 16 K-tiles

  // prologue: tiles 0,1 staged (7 gloads each); vmcnt(7) -> tile 0 ready
#pragma unroll
  for (int h = 0; h < 2; ++h) stageA(0, 0, h);
#pragma unroll
  for (int n = 0; n < 3; ++n) stageB(0, 0, n);
#pragma unroll
  for (int h = 0; h < 2; ++h) stageA(1, 1, h);
#pragma unroll
  for (int n = 0; n < 3; ++n) stageB(1, 1, n);
  asm volatile("s_waitcnt vmcnt(7)" ::: "memory");
  PBAR();

  for (int t = 0; t < NT; ++t) {
    const int cur = t & 1;
    const __bf16* cA = lA + cur * 16384;
    const __bf16* cB = lB + cur * 12288;
    const bool pre = (t + 2 < NT);

    bf16x8 afl[4][2], afh[4][2], bfl[2][2], bfh[2];

    // ---- phase 1: Q1 = mi0-3 x ni0-1 (16 MFMA) ----
#pragma unroll
    for (int mm = 0; mm < 4; ++mm)
#pragma unroll
      for (int ks = 0; ks < 2; ++ks)
        afl[mm][ks] = rdA(cA, wr * 128 + mm * 16 + lr, ks);
#pragma unroll
    for (int ni = 0; ni < 2; ++ni)
#pragma unroll
      for (int ks = 0; ks < 2; ++ks)
        bfl[ni][ks] = rdA(cB, wc * 48 + ni * 16 + lr, ks);
    PBAR(); LGKM();
    __builtin_amdgcn_s_setprio(1);
#pragma unroll
    for (int mm = 0; mm < 4; ++mm)
#pragma unroll
      for (int ni = 0; ni < 2; ++ni)
#pragma unroll
        for (int ks = 0; ks < 2; ++ks)
          acc[mm][ni] = __builtin_amdgcn_mfma_f32_16x16x32_bf16(
              afl[mm][ks], bfl[ni][ks], acc[mm][ni], 0, 0, 0);
    __builtin_amdgcn_s_setprio(0);
    PBAR();

    // ---- phase 2: Q2 = mi0-3 x ni2 (8 MFMA); stage B n0,n1 (t+2) ----
#pragma unroll
    for (int ks = 0; ks < 2; ++ks)
      bfh[ks] = rdA(cB, wc * 48 + 2 * 16 + lr, ks);
    if (pre) { stageB(cur, t + 2, 0); stageB(cur, t + 2, 1); }
    PBAR(); LGKM();
    __builtin_amdgcn_s_setprio(1);
#pragma unroll
    for (int mm = 0; mm < 4; ++mm)
#pragma unroll
      for (int ks = 0; ks < 2; ++ks)
        acc[mm][2] = __builtin_amdgcn_mfma_f32_16x16x32_bf16(
            afl[mm][ks], bfh[ks], acc[mm][2], 0, 0, 0);
    __builtin_amdgcn_s_setprio(0);
    PBAR();

    // ---- phase 3: Q3 = mi4-7 x ni0-1 (16 MFMA); stage B n2 + A h0 (t+2) ----
#pragma unroll
    for (int mm = 0; mm < 4; ++mm)
#pragma unroll
      for (int ks = 0; ks < 2; ++ks)
        afh[mm][ks] = rdA(cA, wr * 128 + (mm + 4) * 16 + lr, ks);
    if (pre) { stageB(cur, t + 2, 2); stageA(cur, t + 2, 0); }
    PBAR(); LGKM();
    __builtin_amdgcn_s_setprio(1);
#pragma unroll
    for (int mm = 0; mm < 4; ++mm)
#pragma unroll
      for (int ni = 0; ni < 2; ++ni)
#pragma unroll
        for (int ks = 0; ks < 2; ++ks)
          acc[mm + 4][ni] = __builtin_amdgcn_mfma_f32_16x16x32_bf16(
              afh[mm][ks], bfl[ni][ks], acc[mm + 4][ni], 0, 0, 0);
    __builtin_amdgcn_s_setprio(0);
    PBAR();

    // ---- phase 4: Q4 = mi4-7 x ni2 (8 MFMA); stage A h1 (t+2); counted vmcnt ----
    if (pre) stageA(cur, t + 2, 1);
    if (pre)                asm volatile("s_waitcnt vmcnt(7)" ::: "memory");
    else if (t + 1 < NT)    asm volatile("s_waitcnt vmcnt(0)" ::: "memory");
    PBAR();
    __builtin_amdgcn_s_setprio(1);
#pragma unroll
    for (int mm = 0; mm < 4; ++mm)
#pragma unroll
      for (int ks = 0; ks < 2; ++ks)
        acc[mm + 4][2] = __builtin_amdgcn_mfma_f32_16x16x32_bf16(
            afh[mm][ks], bfh[ks], acc[mm + 4][2], 0, 0, 0);
    __builtin_amdgcn_s_setprio(0);
    PBAR();
  }

#pragma unroll
  for (int ni = 0; ni < 3; ++ni) {
    int col = o0 + wc * 48 + ni * 16 + lr;     // global col in [0,3072)
    int z = col >> 10, cin = col & 1023;       // uniform z per 16-col group
    const float* bp = (z == 0) ? b0 : (z == 1) ? b1 : b2;
    float bb = bp[cin];
    __bf16* O = QKVp + (size_t)z * 8192 * DM;
#pragma unroll
    for (int mm = 0; mm < 8; ++mm) {
      int row = i0 + wr * 128 + mm * 16 + lg * 4;
#pragma unroll
      for (int r = 0; r < 4; ++r)
        O[(size_t)(row + r) * DM + cin] = (__bf16)(acc[mm][ni][r] + bb);
    }
  }
}

// ---------------- out-proj GEMM: 128x256, BK=64, 8 waves, 4-phase counted-vmcnt ----------------
__global__ __launch_bounds__(512, 2) void gemm_out_kernel(
    const __bf16* __restrict__ A, const __bf16* __restrict__ W,
    const float* __restrict__ bias, float* __restrict__ C) {
  __shared__ __align__(16) __bf16 lA[2 * 128 * 64];   // 32 KB
  __shared__ __align__(16) __bf16 lB[2 * 256 * 64];   // 64 KB
  const int flat = blockIdx.x;                 // 0..255
  const int xcd = flat & 7, idx = flat >> 3;   // idx 0..31
  const int mi = xcd * 8 + (idx & 7);          // 0..63
  const int nig = idx >> 3;                    // 0..3
  const int i0 = mi * 128, o0 = nig * 256;

  const int tid = threadIdx.x;
  const int l = tid & 63, lr = l & 15, lg = l >> 4;
  const int w = tid >> 6;
  const int wr = w >> 2, wc = w & 3;

  f32x4 acc[4][4];
  const f32x4 fzero = {0.f, 0.f, 0.f, 0.f};
#pragma unroll
  for (int mm = 0; mm < 4; ++mm)
#pragma unroll
    for (int ni = 0; ni < 4; ++ni) acc[mm][ni] = fzero;

  const int s_row = tid >> 3;                  // 0..63
  const int s_cc  = tid & 7;
  const __bf16* Ab = A + (size_t)i0 * DM;
  const __bf16* Wb = W + (size_t)o0 * DM;

  auto stageA = [&](int buf, int kt, int h) {  // A half = 64 rows = 1 gload
    int row = h * 64 + s_row;
    gload16(Ab + (size_t)row * DM + kt * 64 + ((s_cc ^ (row & 7)) << 3),
            lA + buf * 8192 + h * 4096 + tid * 8);
  };
  auto stageB = [&](int buf, int kt, int h) {  // B half = 128 rows = 2 gloads
#pragma unroll
    for (int rr = 0; rr < 2; ++rr) {
      int row = h * 128 + rr * 64 + s_row;
      gload16(Wb + (size_t)row * DM + kt * 64 + ((s_cc ^ (row & 7)) << 3),
              lB + buf * 16384 + (h * 128 + rr * 64) * 64 + tid * 8);
    }
  };
  auto rd = [&](const __bf16* base, int row, int ks) {
    int chunk = (ks * 4 + lg) ^ (row & 7);
    return *(const bf16x8*)(base + row * 64 + chunk * 8);
  };

  const int NT = DM / 64;                      // 16

  // prologue: tiles 0,1 staged (6 gloads each); vmcnt(6) -> tile 0 ready
#pragma unroll
  for (int h = 0; h < 2; ++h) { stageA(0, 0, h); stageB(0, 0, h); }
#pragma unroll
  for (int h = 0; h < 2; ++h) { stageA(1, 1, h); stageB(1, 1, h); }
  asm volatile("s_waitcnt vmcnt(6)" ::: "memory");
  PBAR();

  for (int t = 0; t < NT; ++t) {
    const int cur = t & 1;
    const __bf16* cA = lA + cur * 8192;
    const __bf16* cB = lB + cur * 16384;
    const bool pre = (t + 2 < NT);

    bf16x8 afl[2][2], afh[2][2], bfl[2][2], bfh[2][2];

    // ---- phase 1: mi-lo x ni-lo ----
#pragma unroll
    for (int mm = 0; mm < 2; ++mm)
#pragma unroll
      for (int ks = 0; ks < 2; ++ks)
        afl[mm][ks] = rd(cA, wr * 32 + mm * 16 + lr, ks);
#pragma unroll
    for (int ni = 0; ni < 2; ++ni)
#pragma unroll
      for (int ks = 0; ks < 2; ++ks)
        bfl[ni][ks] = rd(cB, wc * 32 + ni * 16 + lr, ks);
    PBAR(); LGKM();
    __builtin_amdgcn_s_setprio(1);
#pragma unroll
    for (int mm = 0; mm < 2; ++mm)
#pragma unroll
      for (int ni = 0; ni < 2; ++ni)
#pragma unroll
        for (int ks = 0; ks < 2; ++ks)
          acc[mm][ni] = __builtin_amdgcn_mfma_f32_16x16x32_bf16(
              afl[mm][ks], bfl[ni][ks], acc[mm][ni], 0, 0, 0);
    __builtin_amdgcn_s_setprio(0);
    PBAR();

    // ---- phase 2: mi-lo x ni-hi; stage Bh0(t+2) ----
#pragma unroll
    for (int ni = 0; ni < 2; ++ni)
#pragma unroll
      for (int ks = 0; ks < 2; ++ks)
        bfh[ni][ks] = rd(cB, 128 + wc * 32 + ni * 16 + lr, ks);
    if (pre) stageB(cur, t + 2, 0);
    PBAR(); LGKM();
    __builtin_amdgcn_s_setprio(1);
#pragma unroll
    for (int mm = 0; mm < 2; ++mm)
#pragma unroll
      for (int ni = 0; ni < 2; ++ni)
#pragma unroll
        for (int ks = 0; ks < 2; ++ks)
          acc[mm][ni + 2] = __builtin_amdgcn_mfma_f32_16x16x32_bf16(
              afl[mm][ks], bfh[ni][ks], acc[mm][ni + 2], 0, 0, 0);
    __builtin_amdgcn_s_setprio(0);
    PBAR();

    // ---- phase 3: mi-hi x ni-lo; stage Ah0,Bh1(t+2) ----
#pragma unroll
    for (int mm = 0; mm < 2; ++mm)
#pragma unroll
      for (int ks = 0; ks < 2; ++ks)
        afh[mm][ks] = rd(cA, 64 + wr * 32 + mm * 16 + lr, ks);
    if (pre) { stageA(cur, t + 2, 0); stageB(cur, t + 2, 1); }
    PBAR(); LGKM();
    __builtin_amdgcn_s_setprio(1);
#pragma unroll
    for (int mm = 0; mm < 2; ++mm)
#pragma unroll
      for (int ni = 0; ni < 2; ++ni)
#pragma unroll
        for (int ks = 0; ks < 2; ++ks)
          acc[mm + 2][ni] = __builtin_amdgcn_mfma_f32_16x16x32_bf16(
              afh[mm][ks], bfl[ni][ks], acc[mm + 2][ni], 0, 0, 0);
    __builtin_amdgcn_s_setprio(0);
    PBAR();

    // ---- phase 4: mi-hi x ni-hi (held regs); stage Ah1(t+2); counted vmcnt ----
    if (pre) stageA(cur, t + 2, 1);
    if (pre)                asm volatile("s_waitcnt vmcnt(6)" ::: "memory");
    else if (t + 1 < NT)    asm volatile("s_waitcnt vmcnt(0)" ::: "memory");
    PBAR();
    __builtin_amdgcn_s_setprio(1);
#pragma unroll
    for (int mm = 0; mm < 2; ++mm)
#pragma unroll
      for (int ni = 0; ni < 2; ++ni)
#pragma unroll
        for (int ks = 0; ks < 2; ++ks)
          acc[mm + 2][ni + 2] = __builtin_amdgcn_mfma_f32_16x16x32_bf16(
              afh[mm][ks], bfh[ni][ks], acc[mm + 2][ni + 2], 0, 0, 0);
    __builtin_amdgcn_s_setprio(0);
    PBAR();
  }

#pragma unroll
  for (int ni = 0; ni < 4; ++ni) {
    int colb = (ni < 2) ? (wc * 32 + ni * 16) : (128 + wc * 32 + (ni - 2) * 16);
    int col = o0 + colb + lr;
    float bb = bias[col];
#pragma unroll
    for (int mm = 0; mm < 4; ++mm) {
      int rowb = (mm < 2) ? (wr * 32 + mm * 16) : (64 + wr * 32 + (mm - 2) * 16);
      int row = i0 + rowb + lg * 4;
#pragma unroll
      for (int r = 0; r < 4; ++r)
        C[(size_t)(row + r) * DM + col] = acc[mm][ni][r] + bb;
    }
  }
}

// ---------------- pass B (FUSED-Q): both kt {31-bx, bx} share one Q stream ----------------
__global__ __launch_bounds__(256) void colstats_kernel(
    const __bf16* __restrict__ Q, const __bf16* __restrict__ K,
    const __bf16* __restrict__ V, __bf16* __restrict__ VT) {
  const int flat = blockIdx.x;
  const int wid = (flat & 7) * 128 + (flat >> 3);  // 0..1023
  const int g = wid >> 4, bx = wid & 15;
  const int h = g & 15, b = g >> 4;
  const int tid = threadIdx.x;
  const int w = tid >> 6, l = tid & 63, lr = l & 15, lg = l >> 4;
  const size_t base = (size_t)b * TSEQ * DM + (size_t)h * HD;

  const int kt1 = 31 - bx, kt2 = bx;
  const int k01 = kt1 * 64, k02 = kt2 * 64;

  __shared__ float part[4][64];
  __shared__ float invc[64];

  bf16x8 kf1[4][2], kf2[4][2];
#pragma unroll
  for (int ct = 0; ct < 4; ++ct)
#pragma unroll
    for (int ks = 0; ks < 2; ++ks) {
      kf1[ct][ks] = *(const bf16x8*)(K + base + (size_t)(k01 + ct * 16 + lr) * DM +
                                     ks * 32 + lg * 8);
      kf2[ct][ks] = *(const bf16x8*)(K + base + (size_t)(k02 + ct * 16 + lr) * DM +
                                     ks * 32 + lg * 8);
    }

  float csum1[4] = {0.f, 0.f, 0.f, 0.f};
  float csum2[4] = {0.f, 0.f, 0.f, 0.f};
  const int nchunks = (TSEQ - k02) >> 4;   // kt2's (larger) range
  for (int jj = w; jj < nchunks; jj += 4) {
    const int qrow = k02 + jj * 16;
    bf16x8 a0 = *(const bf16x8*)(Q + base + (size_t)(qrow + lr) * DM + lg * 8);
    bf16x8 a1 = *(const bf16x8*)(Q + base + (size_t)(qrow + lr) * DM + 32 + lg * 8);

    {
      const bool interior = (jj >= 4);
#pragma unroll
      for (int ct = 0; ct < 4; ++ct) {
        f32x4 s = {0.f, 0.f, 0.f, 0.f};
        s = __builtin_amdgcn_mfma_f32_16x16x32_bf16(a0, kf2[ct][0], s, 0, 0, 0);
        s = __builtin_amdgcn_mfma_f32_16x16x32_bf16(a1, kf2[ct][1], s, 0, 0, 0);
        if (interior) {
#pragma unroll
          for (int r = 0; r < 4; ++r) csum2[ct] += __builtin_amdgcn_exp2f(s[r] * SCL);
        } else {
#pragma unroll
          for (int r = 0; r < 4; ++r) {
            int ql = jj * 16 + lg * 4 + r;
            int kl = ct * 16 + lr;
            float e = __builtin_amdgcn_exp2f(s[r] * SCL);
            csum2[ct] += (ql >= kl) ? e : 0.f;
          }
        }
      }
    }
    if (qrow >= k01) {
      const bool interior = (qrow >= k01 + 64);
#pragma unroll
      for (int ct = 0; ct < 4; ++ct) {
        f32x4 s = {0.f, 0.f, 0.f, 0.f};
        s = __builtin_amdgcn_mfma_f32_16x16x32_bf16(a0, kf1[ct][0], s, 0, 0, 0);
        s = __builtin_amdgcn_mfma_f32_16x16x32_bf16(a1, kf1[ct][1], s, 0, 0, 0);
        if (interior) {
#pragma unroll
          for (int r = 0; r < 4; ++r) csum1[ct] += __builtin_amdgcn_exp2f(s[r] * SCL);
        } else {
#pragma unroll
          for (int r = 0; r < 4; ++r) {
            int ql = (qrow - k01) + lg * 4 + r;
            int kl = ct * 16 + lr;
            float e = __builtin_amdgcn_exp2f(s[r] * SCL);
            csum1[ct] += (ql >= kl) ? e : 0.f;
          }
        }
      }
    }
  }

#pragma unroll
  for (int ct = 0; ct < 4; ++ct) {
    csum1[ct] += __shfl_xor(csum1[ct], 16, 64);
    csum1[ct] += __shfl_xor(csum1[ct], 32, 64);
    csum2[ct] += __shfl_xor(csum2[ct], 16, 64);
    csum2[ct] += __shfl_xor(csum2[ct], 32, 64);
  }

  const int d = tid >> 2, gq = tid & 3;
  if (l < 16) {
#pragma unroll
    for (int ct = 0; ct < 4; ++ct) part[w][ct * 16 + l] = csum1[ct];
  }
  __syncthreads();
  if (tid < 64)
    invc[tid] = 1.0f / (part[0][tid] + part[1][tid] + part[2][tid] + part[3][tid]);
  __syncthreads();
  {
    size_t vtb = (((size_t)(b * NH + h)) * HD + d) * TSEQ + k01 + gq * 16;
#pragma unroll
    for (int kc = 0; kc < 16; kc += 2) {
      int kl = gq * 16 + kc;
      float v0 = (float)V[base + (size_t)(k01 + kl) * DM + d] * invc[kl];
      float v1 = (float)V[base + (size_t)(k01 + kl + 1) * DM + d] * invc[kl + 1];
      bf16x2 o; o[0] = (__bf16)v0; o[1] = (__bf16)v1;
      *(bf16x2*)(VT + vtb + kc) = o;
    }
  }
  __syncthreads();  // invc reads done before overwrite
  if (l < 16) {
#pragma unroll
    for (int ct = 0; ct < 4; ++ct) part[w][ct * 16 + l] = csum2[ct];
  }
  __syncthreads();
  if (tid < 64)
    invc[tid] = 1.0f / (part[0][tid] + part[1][tid] + part[2][tid] + part[3][tid]);
  __syncthreads();
  {
    size_t vtb = (((size_t)(b * NH + h)) * HD + d) * TSEQ + k02 + gq * 16;
#pragma unroll
    for (int kc = 0; kc < 16; kc += 2) {
      int kl = gq * 16 + kc;
      float v0 = (float)V[base + (size_t)(k02 + kl) * DM + d] * invc[kl];
      float v1 = (float)V[base + (size_t)(k02 + kl + 1) * DM + d] * invc[kl + 1];
      bf16x2 o; o[0] = (__bf16)v0; o[1] = (__bf16)v1;
      *(bf16x2*)(VT + vtb + kc) = o;
    }
  }
}

// XOR swizzle (involution) on element index of a [64][64] bf16 tile
__device__ __forceinline__ int swz(int e) { return e ^ (((e >> 6) & 7) << 3); }

// ---------------- pass C (FUSED x2): q-tiles {31-bx, bx} in ONE K-loop ----------------
__global__ __launch_bounds__(256, 4) void ctx_kernel(
    const __bf16* __restrict__ Q, const __bf16* __restrict__ K,
    const __bf16* __restrict__ VT, __bf16* __restrict__ CTX) {
  __shared__ __align__(16) __bf16 lK[4096];
  __shared__ __align__(16) __bf16 lV[4096];
  __shared__ __align__(16) __bf16 lP[8][16 * 88];   // [wave + 4*tile]
  const int flat = blockIdx.x;
  const int wid = (flat & 7) * 128 + (flat >> 3);  // 0..1023
  const int g = wid >> 4, bx = wid & 15;
  const int h = g & 15, b = g >> 4;
  const int tid = threadIdx.x;
  const int w = tid >> 6, l = tid & 63, lr = l & 15, lg = l >> 4;
  const size_t base = (size_t)b * TSEQ * DM + (size_t)h * HD;
  const size_t vtb = ((size_t)(b * NH + h)) * HD * TSEQ;
  __bf16* pw1 = &lP[w][0];
  __bf16* pw2 = &lP[w + 4][0];

  const int qt1 = 31 - bx, qt2 = bx;   // qt1 >= 16 > qt2 always
  const int q01 = qt1 * 64, q02 = qt2 * 64;

  const int srow = w * 8 + (l >> 3);
  const int scol = (((l & 7) ^ (l >> 3)) << 3);

  bf16x8 qf1[2], qf2[2];
#pragma unroll
  for (int ks = 0; ks < 2; ++ks) {
    qf1[ks] = *(const bf16x8*)(Q + base + (size_t)(q01 + w * 16 + lr) * DM + ks * 32 + lg * 8);
    qf2[ks] = *(const bf16x8*)(Q + base + (size_t)(q02 + w * 16 + lr) * DM + ks * 32 + lg * 8);
  }

  f32x4 acc1[4], acc2[4];
  const f32x4 fzero = {0.f, 0.f, 0.f, 0.f};
#pragma unroll
  for (int dt = 0; dt < 4; ++dt) { acc1[dt] = fzero; acc2[dt] = fzero; }

  for (int kt = 0; kt <= qt1; ++kt) {
    const int k0 = kt * 64;
    const bool two = (kt <= qt2);
    __syncthreads();   // prior iter's LDS reads done before overwrite
#pragma unroll
    for (int n = 0; n < 2; ++n) {
      gload16(K + base + (size_t)(k0 + n * 32 + srow) * DM + scol,
              lK + n * 2048 + w * 512);
      gload16(VT + vtb + (size_t)(n * 32 + srow) * TSEQ + k0 + scol,
              lV + n * 2048 + w * 512);
    }
    asm volatile("s_waitcnt vmcnt(0)" ::: "memory");
    __syncthreads();

    const bool diag1 = (kt == qt1), diag2 = (kt == qt2);
#pragma unroll
    for (int ct = 0; ct < 4; ++ct) {
      bf16x8 kb[2];
#pragma unroll
      for (int ks = 0; ks < 2; ++ks) {
        int e = (ct * 16 + lr) * 64 + ks * 32 + lg * 8;
        kb[ks] = *(const bf16x8*)(lK + swz(e));
      }
      {
        f32x4 s = {0.f, 0.f, 0.f, 0.f};
        s = __builtin_amdgcn_mfma_f32_16x16x32_bf16(kb[0], qf1[0], s, 0, 0, 0);
        s = __builtin_amdgcn_mfma_f32_16x16x32_bf16(kb[1], qf1[1], s, 0, 0, 0);
        bf16x4 pk;
        if (diag1) {
#pragma unroll
          for (int r = 0; r < 4; ++r) {
            int ql = w * 16 + lr, kl = ct * 16 + lg * 4 + r;
            pk[r] = (__bf16)((ql >= kl) ? __builtin_amdgcn_exp2f(s[r] * SCL) : 0.f);
          }
        } else {
#pragma unroll
          for (int r = 0; r < 4; ++r)
            pk[r] = (__bf16)__builtin_amdgcn_exp2f(s[r] * SCL);
        }
        *(bf16x4*)(pw1 + lr * 88 + ct * 16 + lg * 4) = pk;
      }
      if (two) {
        f32x4 s = {0.f, 0.f, 0.f, 0.f};
        s = __builtin_amdgcn_mfma_f32_16x16x32_bf16(kb[0], qf2[0], s, 0, 0, 0);
        s = __builtin_amdgcn_mfma_f32_16x16x32_bf16(kb[1], qf2[1], s, 0, 0, 0);
        bf16x4 pk;
        if (diag2) {
#pragma unroll
          for (int r = 0; r < 4; ++r) {
            int ql = w * 16 + lr, kl = ct * 16 + lg * 4 + r;
            pk[r] = (__bf16)((ql >= kl) ? __builtin_amdgcn_exp2f(s[r] * SCL) : 0.f);
          }
        } else {
#pragma unroll
          for (int r = 0; r < 4; ++r)
            pk[r] = (__bf16)__builtin_amdgcn_exp2f(s[r] * SCL);
        }
        *(bf16x4*)(pw2 + lr * 88 + ct * 16 + lg * 4) = pk;
      }
    }
    asm volatile("" ::: "memory");  // same-wave DS in-order: P writes before reads

    bf16x8 pa1[2], pa2[2];
#pragma unroll
    for (int ks = 0; ks < 2; ++ks)
      pa1[ks] = *(const bf16x8*)(pw1 + lr * 88 + ks * 32 + lg * 8);
    if (two) {
#pragma unroll
      for (int ks = 0; ks < 2; ++ks)
        pa2[ks] = *(const bf16x8*)(pw2 + lr * 88 + ks * 32 + lg * 8);
    }
#pragma unroll
    for (int dt = 0; dt < 4; ++dt) {
#pragma unroll
      for (int ks = 0; ks < 2; ++ks) {
        int e = (dt * 16 + lr) * 64 + ks * 32 + lg * 8;
        bf16x8 vb8 = *(const bf16x8*)(lV + swz(e));   // shared by both tiles
        acc1[dt] = __builtin_amdgcn_mfma_f32_16x16x32_bf16(pa1[ks], vb8, acc1[dt], 0, 0, 0);
        if (two)
          acc2[dt] = __builtin_amdgcn_mfma_f32_16x16x32_bf16(pa2[ks], vb8, acc2[dt], 0, 0, 0);
      }
    }
  }

#pragma unroll
  for (int dt = 0; dt < 4; ++dt)
#pragma unroll
    for (int r = 0; r < 4; ++r) {
      CTX[base + (size_t)(q01 + w * 16 + lg * 4 + r) * DM + dt * 16 + lr] = (__bf16)acc1[dt][r];
      CTX[base + (size_t)(q02 + w * 16 + lg * 4 + r) * DM + dt * 16 + lr] = (__bf16)acc2[dt][r];
    }
}

extern "C" void kernel_launch(void* const* d_in, const int* in_sizes, int n_in,
                              void* d_out, int out_size, void* d_ws, size_t ws_size,
                              hipStream_t stream) {
  const float* q  = (const float*)d_in[0];
  const float* Wq = (const float*)d_in[3];
  const float* bq = (const float*)d_in[4];
  const float* Wk = (const float*)d_in[5];
  const float* bk = (const float*)d_in[6];
  const float* Wv = (const float*)d_in[7];
  const float* bv = (const float*)d_in[8];
  const float* Wo = (const float*)d_in[9];
  const float* bo = (const float*)d_in[10];
  float* out = (float*)d_out;

  const size_t NTOK = (size_t)BATCH * TSEQ;  // 8192
  char* ws = (char*)d_ws;
  __bf16* qb   = (__bf16*)ws; ws += NTOK * DM * 2;      // reused as CTX later
  __bf16* Wqkv = (__bf16*)ws; ws += 3 * (size_t)DM * DM * 2;  // [3][1024][1024]
  __bf16* Wob  = (__bf16*)ws; ws += (size_t)DM * DM * 2;      // contiguous after Wqkv
  __bf16* QKVp = (__bf16*)ws; ws += 3 * NTOK * DM * 2;  // [3][8192][1024]
  __bf16* VT   = (__bf16*)ws; ws += (size_t)BATCH * NH * HD * TSEQ * 2;
  __bf16* CTX = qb;  // qb dead after the QKV GEMM

  __bf16* Qp = QKVp;
  __bf16* Kp = QKVp + NTOK * DM;
  __bf16* Vp = QKVp + 2 * NTOK * DM;

  const int nq4 = (int)(NTOK * DM / 4);      // 2097152
  const int nw4 = DM * DM / 4;               // 262144
  const int ncvt = nq4 + 4 * nw4;            // 3145728 -> 12288 blocks
  cvt_all_kernel<<<ncvt / 256, 256, 0, stream>>>(q, Wq, Wk, Wv, Wo, qb, Wqkv,
                                                 nq4, nw4);

  gemm_qkv_kernel<<<512, 512, 0, stream>>>(qb, Wqkv, bq, bk, bv, QKVp);

  colstats_kernel<<<1024, 256, 0, stream>>>(Qp, Kp, Vp, VT);
  ctx_kernel<<<1024, 256, 0, stream>>>(Qp, Kp, VT, CTX);

  gemm_out_kernel<<<256, 512, 0, stream>>>(CTX, Wob, bo, out);
}